// Round 8
// baseline (90.566 us; speedup 1.0000x reference)
//
#include <hip/hip_runtime.h>
#include <math.h>

// ---------------------------------------------------------------------------
// FluxAnomalyPredictionTF: F=3, E=6, H=3, d=2, FF=2048, N=16, T=2046, S=W=1024
// R8: 4 plain dispatches: frontend(+fcc+qkv0) -> layer0 -> layer1 -> final.
// layer block = 32 tokens of one n; 256 thr; ~59 KB LDS -> 2 blocks/CU.
//   A: stage 3-head KV (48KB) -> attention (wave=8 rows, lanes span t)
//   B: oproj+residual+LN1 (in-block, no att round-trip)
//   C: FF 4 passes x 512 rows, chunk-major wcT[4][512] LDS, T=8 tokens/lane
//   D: LN2 -> seq_out + next-layer qkv (l0) / pooled partial (l1)
// R5 lesson fixed: 2 blocks/CU kept, T=8 kept (LDS 12.3K cyc ~ FMA 13.3K cyc).
// ---------------------------------------------------------------------------

#define TL 2046
#define SL 1024

__device__ __forceinline__ float relu_(float a){ return fmaxf(a, 0.f); }
__device__ __forceinline__ float fexp2_(float x){ return __builtin_amdgcn_exp2f(x); }

#define SCQK 1.0201265650432017f  // (1/sqrt(2)) * log2(e)

// ------------------------------ frontend -----------------------------------
// grid 256 = 16 n * 16 stiles ; 192 threads = 3 waves (wave = feature f)
__global__ __launch_bounds__(192) void frontend_kernel(
  const float* __restrict__ x, const float* __restrict__ k64,
  const float* __restrict__ b64, const float* __restrict__ k16, const float* __restrict__ b16,
  const float* __restrict__ k8,  const float* __restrict__ b8,
  const float* __restrict__ kw3, const float* __restrict__ bw3,
  const float* __restrict__ km3, const float* __restrict__ bm3,
  const float* __restrict__ kn3, const float* __restrict__ bn3,
  const float* __restrict__ fc1w, const float* __restrict__ fc1b,
  const float* __restrict__ fc2w, const float* __restrict__ fc2b,
  const float* __restrict__ f1w, const float* __restrict__ f1b,
  const float* __restrict__ f2w,
  const float* __restrict__ inw, const float* __restrict__ inb,
  float* __restrict__ fcc, float* __restrict__ seq,
  float4* __restrict__ kv4, float2* __restrict__ qq)
{
  __shared__ float xt[3][200];
  __shared__ float k64s[3*64*8];
  __shared__ float flat_s[64][44];
  __shared__ float h1_s[64][20];
  __shared__ float seq6[64][6];
  const int tid  = threadIdx.x;
  const int f    = tid >> 6;
  const int lane = tid & 63;
  const int n    = blockIdx.x >> 4;
  const int s0   = (blockIdx.x & 15) << 6;
  const int s    = s0 + lane;

  // fcc[l][j][16]: [0..5]=f1w row j, [6]=f1b[j], [8..13]=f2w[:,j]
  for (int i = blockIdx.x*192 + tid; i < 2*2048*16; i += 256*192){
    int l = i >> 15, r = i & 32767, j = r >> 4, c = r & 15;
    float v = 0.f;
    if (c < 6)       v = f1w[(l*2048 + j)*6 + c];
    else if (c == 6) v = f1b[l*2048 + j];
    else if (c >= 8 && c < 14) v = f2w[(l*6 + (c-8))*2048 + j];
    fcc[i] = v;
  }

  for (int i = tid; i < 600; i += 192){
    int ff = i / 200, pos = i - ff*200;
    int xp = 2*s0 - 39 + pos;
    xt[ff][pos] = (xp >= 0 && xp < TL) ? x[(n*TL + xp)*3 + ff] : 0.f;
  }
  for (int i = tid; i < 1536; i += 192){
    int ff = i >> 9, r = i & 511, t = r >> 3, k = r & 7;
    k64s[i] = k64[k*192 + ff*64 + t];
  }
  __syncthreads();

  float xr[74];
  {
    const int b = 2*lane;
    #pragma unroll
    for (int i = 0; i < 74; i++) xr[i] = xt[f][b + i];
  }

  // ---- wide: 64-tap ----
  float accw[8], acc_e0, acc_e1;
  #pragma unroll
  for (int k = 0; k < 8; k++) accw[k] = b64[k*3 + f];
  acc_e0 = accw[7]; acc_e1 = accw[0];
  {
    const float* kp = &k64s[f*512];
    #pragma unroll
    for (int t = 0; t < 64; t++){
      float4 wa = *(const float4*)(kp + t*8);
      float4 wb = *(const float4*)(kp + t*8 + 4);
      float xm = xr[8 + t];
      accw[0] = fmaf(xm, wa.x, accw[0]);
      accw[1] = fmaf(xm, wa.y, accw[1]);
      accw[2] = fmaf(xm, wa.z, accw[2]);
      accw[3] = fmaf(xm, wa.w, accw[3]);
      accw[4] = fmaf(xm, wb.x, accw[4]);
      accw[5] = fmaf(xm, wb.y, accw[5]);
      accw[6] = fmaf(xm, wb.z, accw[6]);
      accw[7] = fmaf(xm, wb.w, accw[7]);
      acc_e0 = fmaf(xr[6 + t],  wb.w, acc_e0);
      acc_e1 = fmaf(xr[10 + t], wa.x, acc_e1);
    }
  }
  float yw[10];
  yw[0] = (s > 0) ? 5.f*relu_(acc_e0) : 0.f;
  #pragma unroll
  for (int c = 1; c <= 8; c++) yw[c] = 5.f*relu_(accw[c-1]);
  yw[9] = (s < 1023) ? 5.f*relu_(acc_e1) : 0.f;

  // ---- mid: 16-tap ----
  float w16r[16];
  #pragma unroll
  for (int t = 0; t < 16; t++) w16r[t] = k16[f*16 + t];
  const float bb16 = b16[f];
  float ym[10];
  #pragma unroll
  for (int ci = 0; ci < 10; ci++){
    const int b = (ci == 0) ? 54 : ((ci == 9) ? 2 : 8*(ci-1));
    float a = bb16;
    #pragma unroll
    for (int t = 0; t < 16; t++) a = fmaf(xr[b + t], w16r[t], a);
    ym[ci] = relu_(a);
  }
  if (s == 0)    ym[0] = 0.f;
  if (s == 1023) ym[9] = 0.f;

  // ---- nar: 8-tap, max over 4 ----
  float w8r[8];
  #pragma unroll
  for (int t = 0; t < 8; t++) w8r[t] = k8[f*8 + t];
  const float bb8 = b8[f];
  float yn[10];
  #pragma unroll
  for (int ci = 0; ci < 10; ci++){
    float m = -3.0e38f;
    #pragma unroll
    for (int j2 = 0; j2 < 4; j2++){
      const int b = (ci == 0) ? (58 + 2*j2)
                  : ((ci == 9) ? (6 + 2*j2)
                               : (4 + 2*(4*(ci-1) + j2)));
      float a = bb8;
      #pragma unroll
      for (int t = 0; t < 8; t++) a = fmaf(xr[b + t], w8r[t], a);
      m = fmaxf(m, a);
    }
    yn[ci] = relu_(m);
  }
  if (s == 0)    yn[0] = 0.f;
  if (s == 1023) yn[9] = 0.f;

  // ---- conv3 + relu + pool2 -> flat ----
  {
    float c0 = kw3[f*3], c1 = kw3[f*3+1], c2 = kw3[f*3+2], bb = bw3[f];
    #pragma unroll
    for (int q = 0; q < 4; q++){
      float z0 = relu_(fmaf(c0, yw[2*q],   fmaf(c1, yw[2*q+1], fmaf(c2, yw[2*q+2], bb))));
      float z1 = relu_(fmaf(c0, yw[2*q+1], fmaf(c1, yw[2*q+2], fmaf(c2, yw[2*q+3], bb))));
      flat_s[lane][q*3 + f] = fmaxf(z0, z1);
    }
  }
  {
    float c0 = km3[f*3], c1 = km3[f*3+1], c2 = km3[f*3+2], bb = bm3[f];
    #pragma unroll
    for (int q = 0; q < 4; q++){
      float z0 = relu_(fmaf(c0, ym[2*q],   fmaf(c1, ym[2*q+1], fmaf(c2, ym[2*q+2], bb))));
      float z1 = relu_(fmaf(c0, ym[2*q+1], fmaf(c1, ym[2*q+2], fmaf(c2, ym[2*q+3], bb))));
      flat_s[lane][12 + q*3 + f] = fmaxf(z0, z1);
    }
  }
  {
    float c0 = kn3[f*3], c1 = kn3[f*3+1], c2 = kn3[f*3+2], bb = bn3[f];
    #pragma unroll
    for (int q = 0; q < 4; q++){
      float z0 = relu_(fmaf(c0, yn[2*q],   fmaf(c1, yn[2*q+1], fmaf(c2, yn[2*q+2], bb))));
      float z1 = relu_(fmaf(c0, yn[2*q+1], fmaf(c1, yn[2*q+2], fmaf(c2, yn[2*q+3], bb))));
      flat_s[lane][24 + q*3 + f] = fmaxf(z0, z1);
    }
  }
  __syncthreads();

  // ---- fc1 ----
  #pragma unroll
  for (int oi = 0; oi < 6; oi++){
    const int o = 6*f + oi;
    float acc = fc1b[o];
    const float4* wrow = (const float4*)(fc1w + o*36);
    const float4* frow = (const float4*)(&flat_s[lane][0]);
    #pragma unroll
    for (int i = 0; i < 9; i++){
      float4 wv = wrow[i], fv = frow[i];
      acc = fmaf(wv.x, fv.x, acc); acc = fmaf(wv.y, fv.y, acc);
      acc = fmaf(wv.z, fv.z, acc); acc = fmaf(wv.w, fv.w, acc);
    }
    h1_s[lane][o] = relu_(acc);
  }
  __syncthreads();

  // ---- fc2 ----
  #pragma unroll
  for (int ei = 0; ei < 2; ei++){
    const int e = 2*f + ei;
    float acc = fc2b[e];
    #pragma unroll
    for (int o = 0; o < 18; o++) acc = fmaf(h1_s[lane][o], fc2w[e*18 + o], acc);
    float v = acc < 0.f ? 0.f : acc;
    seq[(n*SL + s)*6 + e] = v;
    seq6[lane][e] = v;
  }
  __syncthreads();

  // ---- layer-0 qkv: thread = (head g = f, token = lane) ----
  {
    const int g = f;
    float sv[6];
    #pragma unroll
    for (int e = 0; e < 6; e++) sv[e] = seq6[lane][e];
    const int h2 = 2*g;
    float q0 = inb[h2],   q1 = inb[h2+1];
    float k0 = inb[6+h2], k1 = inb[7+h2];
    float v0 = inb[12+h2], v1 = inb[13+h2];
    #pragma unroll
    for (int e = 0; e < 6; e++){
      q0 = fmaf(sv[e], inw[h2*6 + e],      q0);
      q1 = fmaf(sv[e], inw[(h2+1)*6 + e],  q1);
      k0 = fmaf(sv[e], inw[(6+h2)*6 + e],  k0);
      k1 = fmaf(sv[e], inw[(7+h2)*6 + e],  k1);
      v0 = fmaf(sv[e], inw[(12+h2)*6 + e], v0);
      v1 = fmaf(sv[e], inw[(13+h2)*6 + e], v1);
    }
    const int nh = n*3 + g;
    kv4[nh*SL + s] = make_float4(k0*SCQK, k1*SCQK, v0, v1);
    qq [nh*SL + s] = make_float2(q0, q1);
  }
}

// ------------------------------ layer ---------------------------------------
// grid 512 = 16 n x 32 token-tiles(32 tok); 256 thr = 4 waves; ~59 KB LDS.
__global__ __launch_bounds__(256, 2) void layer_kernel(
  const float* __restrict__ seq_in, const float4* __restrict__ kv_in,
  const float2* __restrict__ q_in, const float* __restrict__ fccL,
  const float* __restrict__ owL, const float* __restrict__ obL,
  const float* __restrict__ l1wL, const float* __restrict__ l1bL,
  const float* __restrict__ f2bL, const float* __restrict__ l2wL,
  const float* __restrict__ l2bL,
  const float* __restrict__ WqN, const float* __restrict__ BqN,
  float* __restrict__ seq_out, float4* __restrict__ kv_out,
  float2* __restrict__ q_out, float* __restrict__ partial, int mode)
{
  __shared__ float4 sKV[3072];   // 48 KB; FF phase aliases as wcT[4][512]
  __shared__ float  redA[2304];  // attn reduce; FF reduce aliases (768)
  __shared__ float  attR[192];   // [32 tok][6]
  __shared__ float  sM[192];     // [32 tok][6]  LN1 output
  __shared__ float  fin[192];    // [32 tok][6]  LN2 output
  const int tid  = threadIdx.x;
  const int w    = tid >> 6;
  const int lane = tid & 63;
  const int n    = blockIdx.x >> 5;
  const int tok0 = (blockIdx.x & 31) << 5;

  // ---- A: stage 3-head KV ----
  for (int i = tid; i < 3072; i += 256)
    sKV[i] = kv_in[(n*3 + (i >> 10))*SL + (i & 1023)];
  __syncthreads();

  // ---- A2: attention; wave w -> rows tok0+w*8..+8, 3 heads ----
  {
    const int r0 = tok0 + w*8;
    #pragma unroll
    for (int h = 0; h < 3; h++){
      float q0[8], q1[8];
      {
        const float2* qp = q_in + (n*3 + h)*SL + r0;
        #pragma unroll
        for (int r = 0; r < 8; r++){ float2 qv = qp[r]; q0[r] = qv.x; q1[r] = qv.y; }
      }
      float lv[8], o0[8], o1[8];
      #pragma unroll
      for (int r = 0; r < 8; r++){ lv[r] = 0.f; o0[r] = 0.f; o1[r] = 0.f; }
      #pragma unroll 2
      for (int i = 0; i < 16; i++){
        float4 K = sKV[h*1024 + i*64 + lane];
        #pragma unroll
        for (int r = 0; r < 8; r++){
          float sc = fmaf(q0[r], K.x, q1[r]*K.y);
          float p  = fexp2_(sc);
          lv[r] += p;
          o0[r] = fmaf(p, K.z, o0[r]);
          o1[r] = fmaf(p, K.w, o1[r]);
        }
      }
      #pragma unroll
      for (int r = 0; r < 8; r++){
        lv[r] += __shfl_xor(lv[r], 1); lv[r] += __shfl_xor(lv[r], 2); lv[r] += __shfl_xor(lv[r], 4);
        o0[r] += __shfl_xor(o0[r], 1); o0[r] += __shfl_xor(o0[r], 2); o0[r] += __shfl_xor(o0[r], 4);
        o1[r] += __shfl_xor(o1[r], 1); o1[r] += __shfl_xor(o1[r], 2); o1[r] += __shfl_xor(o1[r], 4);
      }
      {
        const int g = lane >> 3;
        const int base = ((w*3 + h)*8 + g)*24;
        #pragma unroll
        for (int r = 0; r < 8; r++){
          if ((lane & 7) == r){          // static reg index, predicated store
            redA[base + r*3 + 0] = lv[r];
            redA[base + r*3 + 1] = o0[r];
            redA[base + r*3 + 2] = o1[r];
          }
        }
      }
    }
  }
  __syncthreads();
  if (tid < 96){
    const int w2 = tid/24, rem = tid%24, h2 = rem>>3, r2 = rem&7;
    const int base = ((w2*3 + h2)*8)*24 + r2*3;
    float L = 0.f, O0 = 0.f, O1 = 0.f;
    #pragma unroll
    for (int g = 0; g < 8; g++){
      L  += redA[base + g*24];
      O0 += redA[base + g*24 + 1];
      O1 += redA[base + g*24 + 2];
    }
    const float inv = 1.0f / L;
    attR[(w2*8 + r2)*6 + 2*h2]     = O0*inv;
    attR[(w2*8 + r2)*6 + 2*h2 + 1] = O1*inv;
  }
  __syncthreads();

  // ---- B: oproj + residual + LN1 -> sM ----
  if (tid < 32){
    const int token = n*SL + tok0 + tid;
    float av[6];
    #pragma unroll
    for (int e = 0; e < 6; e++) av[e] = attR[tid*6 + e];
    float y[6]; float mu = 0.f;
    #pragma unroll
    for (int e = 0; e < 6; e++){
      float o = obL[e];
      #pragma unroll
      for (int e2 = 0; e2 < 6; e2++) o = fmaf(av[e2], owL[e*6 + e2], o);
      y[e] = seq_in[token*6 + e] + o;
      mu += y[e];
    }
    mu *= (1.f/6.f);
    float var = 0.f;
    #pragma unroll
    for (int e = 0; e < 6; e++){ float d = y[e] - mu; var = fmaf(d, d, var); }
    var *= (1.f/6.f);
    float rstd = rsqrtf(var + 1e-5f);
    #pragma unroll
    for (int e = 0; e < 6; e++)
      sM[tid*6 + e] = (y[e] - mu)*rstd*l1wL[e] + l1bL[e];
  }

  // ---- C: FF, 4 passes of 512 rows; chunk-major wcT[4][512]; T=8 tok/lane --
  // lane = tg8(>>4, 4 token-groups of 8) x ss(&15, 16 row-subslices)
  // wave w -> rows [w*128, w*128+128) of each pass.
  float4* wcT = sKV;                    // alias: wcT[word][row] = wcT[word*512+row]
  const int tg8 = lane >> 4, ss = lane & 15;
  float acc[8][6];
  #pragma unroll
  for (int t = 0; t < 8; t++)
    #pragma unroll
    for (int e = 0; e < 6; e++) acc[t][e] = 0.f;
  float sv[8][6];

  const float4* FC = (const float4*)fccL;  // [2048 rows][4 words]
  #pragma unroll 1
  for (int p = 0; p < 4; p++){
    __syncthreads();                       // prior users of sKV done
    for (int i = tid; i < 2048; i += 256)
      wcT[(i & 3)*512 + (i >> 2)] = FC[p*2048 + i];
    __syncthreads();
    if (p == 0){
      const float* sp = &sM[tg8*8*6];
      #pragma unroll
      for (int t = 0; t < 8; t++)
        #pragma unroll
        for (int e = 0; e < 6; e++) sv[t][e] = sp[t*6 + e];
    }
    #pragma unroll 2
    for (int i = 0; i < 8; i++){
      const int r = w*128 + ss + i*16;
      float4 w0 = wcT[r], w1 = wcT[512 + r], w2 = wcT[1024 + r], w3 = wcT[1536 + r];
      #pragma unroll
      for (int t = 0; t < 8; t++){
        float h = w1.z;
        h = fmaf(sv[t][0], w0.x, h); h = fmaf(sv[t][1], w0.y, h);
        h = fmaf(sv[t][2], w0.z, h); h = fmaf(sv[t][3], w0.w, h);
        h = fmaf(sv[t][4], w1.x, h); h = fmaf(sv[t][5], w1.y, h);
        h = relu_(h);
        acc[t][0] = fmaf(h, w2.x, acc[t][0]); acc[t][1] = fmaf(h, w2.y, acc[t][1]);
        acc[t][2] = fmaf(h, w2.z, acc[t][2]); acc[t][3] = fmaf(h, w2.w, acc[t][3]);
        acc[t][4] = fmaf(h, w3.x, acc[t][4]); acc[t][5] = fmaf(h, w3.y, acc[t][5]);
      }
    }
  }

  // reduce over ss (lane bits 0..3) -> ss==0 lanes hold wave partials
  #pragma unroll
  for (int t = 0; t < 8; t++)
    #pragma unroll
    for (int e = 0; e < 6; e++){
      acc[t][e] += __shfl_xor(acc[t][e], 1); acc[t][e] += __shfl_xor(acc[t][e], 2);
      acc[t][e] += __shfl_xor(acc[t][e], 4); acc[t][e] += __shfl_xor(acc[t][e], 8);
    }
  __syncthreads();
  float* redF = redA;                  // [4 w][4 tg8][48]
  if (ss == 0){
    #pragma unroll
    for (int t = 0; t < 8; t++)
      #pragma unroll
      for (int e = 0; e < 6; e++) redF[(w*4 + tg8)*48 + t*6 + e] = acc[t][e];
  }
  __syncthreads();

  // ---- D: cross-wave sum + residual + LN2 -> fin ----
  if (tid < 32){
    float y[6]; float mu = 0.f;
    #pragma unroll
    for (int e = 0; e < 6; e++){
      float v = sM[tid*6 + e] + f2bL[e];
      #pragma unroll
      for (int wv = 0; wv < 4; wv++)
        v += redF[(wv*4 + (tid >> 3))*48 + (tid & 7)*6 + e];
      y[e] = v; mu += v;
    }
    mu *= (1.f/6.f);
    float var = 0.f;
    #pragma unroll
    for (int e = 0; e < 6; e++){ float d = y[e] - mu; var = fmaf(d, d, var); }
    var *= (1.f/6.f);
    float rstd = rsqrtf(var + 1e-5f);
    #pragma unroll
    for (int e = 0; e < 6; e++){
      float v = (y[e] - mu)*rstd*l2wL[e] + l2bL[e];
      fin[tid*6 + e] = v;
      if (mode == 0) seq_out[(n*SL + tok0 + tid)*6 + e] = v;
    }
  }
  __syncthreads();

  if (mode == 0){
    // next-layer qkv for this block's 32 tokens: tid<96 = (head g, token t32)
    if (tid < 96){
      const int g = tid >> 5, t32 = tid & 31;
      float sv2[6];
      #pragma unroll
      for (int e = 0; e < 6; e++) sv2[e] = fin[t32*6 + e];
      const int h2 = 2*g;
      float q0 = BqN[h2],   q1 = BqN[h2+1];
      float k0 = BqN[6+h2], k1 = BqN[7+h2];
      float v0 = BqN[12+h2], v1 = BqN[13+h2];
      #pragma unroll
      for (int e = 0; e < 6; e++){
        q0 = fmaf(sv2[e], WqN[h2*6 + e],      q0);
        q1 = fmaf(sv2[e], WqN[(h2+1)*6 + e],  q1);
        k0 = fmaf(sv2[e], WqN[(6+h2)*6 + e],  k0);
        k1 = fmaf(sv2[e], WqN[(7+h2)*6 + e],  k1);
        v0 = fmaf(sv2[e], WqN[(12+h2)*6 + e], v0);
        v1 = fmaf(sv2[e], WqN[(13+h2)*6 + e], v1);
      }
      const int idx = (n*3 + g)*SL + tok0 + t32;
      kv_out[idx] = make_float4(k0*SCQK, k1*SCQK, v0, v1);
      q_out [idx] = make_float2(q0, q1);
    }
  } else {
    // pooled partial for this block (sum of 32 tokens' LN2 output)
    if (tid < 6){
      float s = 0.f;
      #pragma unroll
      for (int t = 0; t < 32; t++) s += fin[t*6 + tid];
      partial[blockIdx.x*6 + tid] = s;
    }
  }
}

// ------------------------------- head ----------------------------------------
// 1 block, 256 thr: sum 32 partials per n, relu-mean, classifier, log_softmax.
__global__ __launch_bounds__(256) void final_kernel(
  const float* __restrict__ partial, const float* __restrict__ o1w,
  const float* __restrict__ o1b, const float* __restrict__ o2w,
  float* __restrict__ out)
{
  __shared__ float pooled[16][6];
  const int tid = threadIdx.x;
  if (tid < 96){
    const int n = tid / 6, e = tid - n*6;
    float s = 0.f;
    #pragma unroll
    for (int g = 0; g < 32; g++) s += partial[(n*32 + g)*6 + e];
    pooled[n][e] = fmaxf(s * (1.f/1024.f), 0.f);
  }
  __syncthreads();
  if (tid < 16){
    const int n = tid;
    float o1[7];
    #pragma unroll
    for (int o = 0; o < 7; o++){
      float a = o1b[o];
      #pragma unroll
      for (int e2 = 0; e2 < 6; e2++) a = fmaf(pooled[n][e2], o1w[o*6 + e2], a);
      o1[o] = relu_(a);
    }
    float lg[4];
    #pragma unroll
    for (int c = 0; c < 4; c++){
      float a = 0.f;
      #pragma unroll
      for (int o = 0; o < 7; o++) a = fmaf(o1[o], o2w[c*7 + o], a);
      lg[c] = a;
    }
    float m = fmaxf(fmaxf(lg[0], lg[1]), fmaxf(lg[2], lg[3]));
    float sum = 0.f;
    #pragma unroll
    for (int c = 0; c < 4; c++) sum += expf(lg[c] - m);
    float lse = m + logf(sum);
    #pragma unroll
    for (int c = 0; c < 4; c++) out[n*4 + c] = lg[c] - lse;
  }
}

// ------------------------------- launch --------------------------------------
extern "C" void kernel_launch(void* const* d_in, const int* in_sizes, int n_in,
                              void* d_out, int out_size, void* d_ws, size_t ws_size,
                              hipStream_t stream)
{
  const float* x    = (const float*)d_in[0];
  const float* k64  = (const float*)d_in[1];
  const float* b64  = (const float*)d_in[2];
  const float* k16  = (const float*)d_in[3];
  const float* b16  = (const float*)d_in[4];
  const float* k8   = (const float*)d_in[5];
  const float* b8   = (const float*)d_in[6];
  const float* kw3  = (const float*)d_in[7];
  const float* bw3  = (const float*)d_in[8];
  const float* km3  = (const float*)d_in[9];
  const float* bm3  = (const float*)d_in[10];
  const float* kn3  = (const float*)d_in[11];
  const float* bn3  = (const float*)d_in[12];
  const float* fc1w = (const float*)d_in[13];
  const float* fc1b = (const float*)d_in[14];
  const float* fc2w = (const float*)d_in[15];
  const float* fc2b = (const float*)d_in[16];
  const float* inw  = (const float*)d_in[17];
  const float* inb  = (const float*)d_in[18];
  const float* ow   = (const float*)d_in[19];
  const float* ob   = (const float*)d_in[20];
  const float* l1w  = (const float*)d_in[21];
  const float* l1b  = (const float*)d_in[22];
  const float* l2w  = (const float*)d_in[23];
  const float* l2b  = (const float*)d_in[24];
  const float* f1w  = (const float*)d_in[25];
  const float* f1b  = (const float*)d_in[26];
  const float* f2w  = (const float*)d_in[27];
  const float* f2b  = (const float*)d_in[28];
  const float* o1w  = (const float*)d_in[29];
  const float* o1b  = (const float*)d_in[30];
  const float* o2w  = (const float*)d_in[31];
  float* out = (float*)d_out;

  float* w = (float*)d_ws;
  float*  seq_a   = w;                       // 98304
  float*  seq_b   = w + 98304;               // 98304
  float*  fcc     = w + 196608;              // 65536
  float4* kv4a    = (float4*)(w + 262144);   // 196608 fl
  float2* qqa     = (float2*)(w + 458752);   // 98304 fl
  float4* kv4b    = (float4*)(w + 557056);   // 196608 fl
  float2* qqb     = (float2*)(w + 753664);   // 98304 fl
  float*  partial = w + 851968;              // 3072
  // total ~855K floats ~= 3.4 MB

  frontend_kernel<<<256, 192, 0, stream>>>(x, k64, b64, k16, b16, k8, b8,
      kw3, bw3, km3, bm3, kn3, bn3, fc1w, fc1b, fc2w, fc2b,
      f1w, f1b, f2w, inw, inb, fcc, seq_a, kv4a, qqa);

  layer_kernel<<<512, 256, 0, stream>>>(seq_a, kv4a, qqa, fcc,
      ow, ob, l1w, l1b, f2b, l2w, l2b,
      inw + 108, inb + 18, seq_b, kv4b, qqb, partial, 0);

  layer_kernel<<<512, 256, 0, stream>>>(seq_b, kv4b, qqb, fcc + 32768,
      ow + 36, ob + 6, l1w + 6, l1b + 6, f2b + 6, l2w + 6, l2b + 6,
      (const float*)nullptr, (const float*)nullptr,
      (float*)nullptr, (float4*)nullptr, (float2*)nullptr, partial, 1);

  final_kernel<<<1, 256, 0, stream>>>(partial, o1w, o1b, o2w, out);
}

// Round 9
// 77.668 us; speedup vs baseline: 1.1661x; 1.1661x over previous
//
#include <hip/hip_runtime.h>
#include <math.h>

// ---------------------------------------------------------------------------
// FluxAnomalyPredictionTF: F=3, E=6, H=3, d=2, FF=2048, N=16, T=2046, S=W=1024
// R9 = R4 structure (7 dispatches, boundaries measured cheap) with occupancy
// fixes on the two big kernels:
//   attn: 512 thr (8 waves, 8 rows/wave) -> 24 waves/CU (was 12);
//         xor1/xor2 reduce via DPP quad_perm (VALU pipe, not DS).
//   ff:   512 thr (8 waves, 64 rows/wave) -> 16 waves/CU (was 8); same AI.
// ---------------------------------------------------------------------------

#define TL 2046
#define SL 1024

__device__ __forceinline__ float relu_(float a){ return fmaxf(a, 0.f); }
__device__ __forceinline__ float fexp2_(float x){ return __builtin_amdgcn_exp2f(x); }
// DPP cross-lane adds on the VALU pipe (quad_perm): xor1 = [1,0,3,2] = 0xB1,
// xor2 = [2,3,0,1] = 0x4E.
__device__ __forceinline__ float dpp_xadd1(float x){
  return x + __int_as_float(__builtin_amdgcn_update_dpp(
      0, __float_as_int(x), 0xB1, 0xF, 0xF, true));
}
__device__ __forceinline__ float dpp_xadd2(float x){
  return x + __int_as_float(__builtin_amdgcn_update_dpp(
      0, __float_as_int(x), 0x4E, 0xF, 0xF, true));
}

#define SCQK 1.0201265650432017f  // (1/sqrt(2)) * log2(e)

// ------------------------------ frontend -----------------------------------
__global__ __launch_bounds__(192) void frontend_kernel(
  const float* __restrict__ x, const float* __restrict__ k64,
  const float* __restrict__ b64, const float* __restrict__ k16, const float* __restrict__ b16,
  const float* __restrict__ k8,  const float* __restrict__ b8,
  const float* __restrict__ kw3, const float* __restrict__ bw3,
  const float* __restrict__ km3, const float* __restrict__ bm3,
  const float* __restrict__ kn3, const float* __restrict__ bn3,
  const float* __restrict__ fc1w, const float* __restrict__ fc1b,
  const float* __restrict__ fc2w, const float* __restrict__ fc2b,
  const float* __restrict__ f1w, const float* __restrict__ f1b,
  const float* __restrict__ f2w,
  const float* __restrict__ inw, const float* __restrict__ inb,
  float* __restrict__ fcc, float* __restrict__ seq,
  float4* __restrict__ kv4, float2* __restrict__ qq)
{
  __shared__ float xt[3][200];
  __shared__ float k64s[3*64*8];
  __shared__ float flat_s[64][44];
  __shared__ float h1_s[64][20];
  __shared__ float seq6[64][6];
  const int tid  = threadIdx.x;
  const int f    = tid >> 6;
  const int lane = tid & 63;
  const int n    = blockIdx.x >> 4;
  const int s0   = (blockIdx.x & 15) << 6;
  const int s    = s0 + lane;

  // fcc[l][j][16]: [0..5]=f1w row j, [6]=f1b[j], [8..13]=f2w[:,j]
  for (int i = blockIdx.x*192 + tid; i < 2*2048*16; i += 256*192){
    int l = i >> 15, r = i & 32767, j = r >> 4, c = r & 15;
    float v = 0.f;
    if (c < 6)       v = f1w[(l*2048 + j)*6 + c];
    else if (c == 6) v = f1b[l*2048 + j];
    else if (c >= 8 && c < 14) v = f2w[(l*6 + (c-8))*2048 + j];
    fcc[i] = v;
  }

  for (int i = tid; i < 600; i += 192){
    int ff = i / 200, pos = i - ff*200;
    int xp = 2*s0 - 39 + pos;
    xt[ff][pos] = (xp >= 0 && xp < TL) ? x[(n*TL + xp)*3 + ff] : 0.f;
  }
  for (int i = tid; i < 1536; i += 192){
    int ff = i >> 9, r = i & 511, t = r >> 3, k = r & 7;
    k64s[i] = k64[k*192 + ff*64 + t];
  }
  __syncthreads();

  float xr[74];
  {
    const int b = 2*lane;
    #pragma unroll
    for (int i = 0; i < 74; i++) xr[i] = xt[f][b + i];
  }

  // ---- wide: 64-tap ----
  float accw[8], acc_e0, acc_e1;
  #pragma unroll
  for (int k = 0; k < 8; k++) accw[k] = b64[k*3 + f];
  acc_e0 = accw[7]; acc_e1 = accw[0];
  {
    const float* kp = &k64s[f*512];
    #pragma unroll
    for (int t = 0; t < 64; t++){
      float4 wa = *(const float4*)(kp + t*8);
      float4 wb = *(const float4*)(kp + t*8 + 4);
      float xm = xr[8 + t];
      accw[0] = fmaf(xm, wa.x, accw[0]);
      accw[1] = fmaf(xm, wa.y, accw[1]);
      accw[2] = fmaf(xm, wa.z, accw[2]);
      accw[3] = fmaf(xm, wa.w, accw[3]);
      accw[4] = fmaf(xm, wb.x, accw[4]);
      accw[5] = fmaf(xm, wb.y, accw[5]);
      accw[6] = fmaf(xm, wb.z, accw[6]);
      accw[7] = fmaf(xm, wb.w, accw[7]);
      acc_e0 = fmaf(xr[6 + t],  wb.w, acc_e0);
      acc_e1 = fmaf(xr[10 + t], wa.x, acc_e1);
    }
  }
  float yw[10];
  yw[0] = (s > 0) ? 5.f*relu_(acc_e0) : 0.f;
  #pragma unroll
  for (int c = 1; c <= 8; c++) yw[c] = 5.f*relu_(accw[c-1]);
  yw[9] = (s < 1023) ? 5.f*relu_(acc_e1) : 0.f;

  // ---- mid: 16-tap ----
  float w16r[16];
  #pragma unroll
  for (int t = 0; t < 16; t++) w16r[t] = k16[f*16 + t];
  const float bb16 = b16[f];
  float ym[10];
  #pragma unroll
  for (int ci = 0; ci < 10; ci++){
    const int b = (ci == 0) ? 54 : ((ci == 9) ? 2 : 8*(ci-1));
    float a = bb16;
    #pragma unroll
    for (int t = 0; t < 16; t++) a = fmaf(xr[b + t], w16r[t], a);
    ym[ci] = relu_(a);
  }
  if (s == 0)    ym[0] = 0.f;
  if (s == 1023) ym[9] = 0.f;

  // ---- nar: 8-tap, max over 4 ----
  float w8r[8];
  #pragma unroll
  for (int t = 0; t < 8; t++) w8r[t] = k8[f*8 + t];
  const float bb8 = b8[f];
  float yn[10];
  #pragma unroll
  for (int ci = 0; ci < 10; ci++){
    float m = -3.0e38f;
    #pragma unroll
    for (int j2 = 0; j2 < 4; j2++){
      const int b = (ci == 0) ? (58 + 2*j2)
                  : ((ci == 9) ? (6 + 2*j2)
                               : (4 + 2*(4*(ci-1) + j2)));
      float a = bb8;
      #pragma unroll
      for (int t = 0; t < 8; t++) a = fmaf(xr[b + t], w8r[t], a);
      m = fmaxf(m, a);
    }
    yn[ci] = relu_(m);
  }
  if (s == 0)    yn[0] = 0.f;
  if (s == 1023) yn[9] = 0.f;

  // ---- conv3 + relu + pool2 -> flat ----
  {
    float c0 = kw3[f*3], c1 = kw3[f*3+1], c2 = kw3[f*3+2], bb = bw3[f];
    #pragma unroll
    for (int q = 0; q < 4; q++){
      float z0 = relu_(fmaf(c0, yw[2*q],   fmaf(c1, yw[2*q+1], fmaf(c2, yw[2*q+2], bb))));
      float z1 = relu_(fmaf(c0, yw[2*q+1], fmaf(c1, yw[2*q+2], fmaf(c2, yw[2*q+3], bb))));
      flat_s[lane][q*3 + f] = fmaxf(z0, z1);
    }
  }
  {
    float c0 = km3[f*3], c1 = km3[f*3+1], c2 = km3[f*3+2], bb = bm3[f];
    #pragma unroll
    for (int q = 0; q < 4; q++){
      float z0 = relu_(fmaf(c0, ym[2*q],   fmaf(c1, ym[2*q+1], fmaf(c2, ym[2*q+2], bb))));
      float z1 = relu_(fmaf(c0, ym[2*q+1], fmaf(c1, ym[2*q+2], fmaf(c2, ym[2*q+3], bb))));
      flat_s[lane][12 + q*3 + f] = fmaxf(z0, z1);
    }
  }
  {
    float c0 = kn3[f*3], c1 = kn3[f*3+1], c2 = kn3[f*3+2], bb = bn3[f];
    #pragma unroll
    for (int q = 0; q < 4; q++){
      float z0 = relu_(fmaf(c0, yn[2*q],   fmaf(c1, yn[2*q+1], fmaf(c2, yn[2*q+2], bb))));
      float z1 = relu_(fmaf(c0, yn[2*q+1], fmaf(c1, yn[2*q+2], fmaf(c2, yn[2*q+3], bb))));
      flat_s[lane][24 + q*3 + f] = fmaxf(z0, z1);
    }
  }
  __syncthreads();

  // ---- fc1 ----
  #pragma unroll
  for (int oi = 0; oi < 6; oi++){
    const int o = 6*f + oi;
    float acc = fc1b[o];
    const float4* wrow = (const float4*)(fc1w + o*36);
    const float4* frow = (const float4*)(&flat_s[lane][0]);
    #pragma unroll
    for (int i = 0; i < 9; i++){
      float4 wv = wrow[i], fv = frow[i];
      acc = fmaf(wv.x, fv.x, acc); acc = fmaf(wv.y, fv.y, acc);
      acc = fmaf(wv.z, fv.z, acc); acc = fmaf(wv.w, fv.w, acc);
    }
    h1_s[lane][o] = relu_(acc);
  }
  __syncthreads();

  // ---- fc2 ----
  #pragma unroll
  for (int ei = 0; ei < 2; ei++){
    const int e = 2*f + ei;
    float acc = fc2b[e];
    #pragma unroll
    for (int o = 0; o < 18; o++) acc = fmaf(h1_s[lane][o], fc2w[e*18 + o], acc);
    float v = acc < 0.f ? 0.f : acc;
    seq[(n*SL + s)*6 + e] = v;
    seq6[lane][e] = v;
  }
  __syncthreads();

  // ---- layer-0 qkv: thread = (head g = f, token = lane) ----
  {
    const int g = f;
    float sv[6];
    #pragma unroll
    for (int e = 0; e < 6; e++) sv[e] = seq6[lane][e];
    const int h2 = 2*g;
    float q0 = inb[h2],   q1 = inb[h2+1];
    float k0 = inb[6+h2], k1 = inb[7+h2];
    float v0 = inb[12+h2], v1 = inb[13+h2];
    #pragma unroll
    for (int e = 0; e < 6; e++){
      q0 = fmaf(sv[e], inw[h2*6 + e],      q0);
      q1 = fmaf(sv[e], inw[(h2+1)*6 + e],  q1);
      k0 = fmaf(sv[e], inw[(6+h2)*6 + e],  k0);
      k1 = fmaf(sv[e], inw[(7+h2)*6 + e],  k1);
      v0 = fmaf(sv[e], inw[(12+h2)*6 + e], v0);
      v1 = fmaf(sv[e], inw[(13+h2)*6 + e], v1);
    }
    const int nh = n*3 + g;
    kv4[nh*SL + s] = make_float4(k0*SCQK, k1*SCQK, v0, v1);
    qq [nh*SL + s] = make_float2(q0, q1);
  }
}

// ------------------------------ attention ----------------------------------
// grid (16 rb(64 rows), 3 h, 16 n); 512 thr = 8 waves -> 24 waves/CU.
// Wave owns 8 q-rows; lanes span t. Reduce: xor1/xor2 on DPP (VALU pipe),
// xor4 via shfl, then 8-group LDS finish.
__global__ __launch_bounds__(512, 4) void attn_kernel(
  const float4* __restrict__ kv4, const float2* __restrict__ qq,
  float* __restrict__ att_out)
{
  __shared__ float4 sKV[1024];          // 16 KB
  __shared__ float red[8][8][8][3];     // [wave][group][row][val]
  const int tid  = threadIdx.x;
  const int w    = tid >> 6;
  const int lane = tid & 63;
  const int rb   = blockIdx.x << 6;
  const int h    = blockIdx.y;
  const int n    = blockIdx.z;
  const int nh   = n*3 + h;

  const float4* kvp = kv4 + nh*SL;
  sKV[tid]       = kvp[tid];
  sKV[tid + 512] = kvp[tid + 512];

  const int r0 = rb + w*8;
  float q0[8], q1[8];
  {
    const float2* qp = qq + nh*SL + r0;
    #pragma unroll
    for (int r = 0; r < 8; r++){ float2 qv = qp[r]; q0[r] = qv.x; q1[r] = qv.y; }
  }
  __syncthreads();

  float lv[8], o0[8], o1[8];
  #pragma unroll
  for (int r = 0; r < 8; r++){ lv[r] = 0.f; o0[r] = 0.f; o1[r] = 0.f; }

  #pragma unroll 2
  for (int i = 0; i < 16; i++){
    float4 K = sKV[i*64 + lane];
    #pragma unroll
    for (int r = 0; r < 8; r++){
      float sc = fmaf(q0[r], K.x, q1[r]*K.y);
      float p  = fexp2_(sc);
      lv[r] += p;
      o0[r] = fmaf(p, K.z, o0[r]);
      o1[r] = fmaf(p, K.w, o1[r]);
    }
  }

  // reduce to 8-lane groups: DPP xor1, DPP xor2, shfl xor4
  #pragma unroll
  for (int r = 0; r < 8; r++){
    lv[r] = dpp_xadd1(lv[r]); lv[r] = dpp_xadd2(lv[r]); lv[r] += __shfl_xor(lv[r], 4);
    o0[r] = dpp_xadd1(o0[r]); o0[r] = dpp_xadd2(o0[r]); o0[r] += __shfl_xor(o0[r], 4);
    o1[r] = dpp_xadd1(o1[r]); o1[r] = dpp_xadd2(o1[r]); o1[r] += __shfl_xor(o1[r], 4);
  }
  {
    const int g = lane >> 3;
    #pragma unroll
    for (int r = 0; r < 8; r++){
      if ((lane & 7) == r){          // static reg index, predicated store
        red[w][g][r][0] = lv[r];
        red[w][g][r][1] = o0[r];
        red[w][g][r][2] = o1[r];
      }
    }
  }
  __syncthreads();

  if (tid < 64){
    const int ww = tid >> 3, r = tid & 7;
    float L = 0.f, O0 = 0.f, O1 = 0.f;
    #pragma unroll
    for (int g = 0; g < 8; g++){
      L  += red[ww][g][r][0];
      O0 += red[ww][g][r][1];
      O1 += red[ww][g][r][2];
    }
    const float inv = 1.0f / L;
    float* orow = att_out + (n*SL + rb + tid)*6 + 2*h;
    orow[0] = O0*inv; orow[1] = O1*inv;
  }
}

// ------------------- fused oproj+LN1 + FF partial ---------------------------
// grid 512 = 128 token-tiles(128 tok) * 4 j-slices(512 rows); 512 thr = 8
// waves -> 16 waves/CU (32KB LDS, 2 blocks/CU). Wave w -> rows [w*64,w*64+64);
// lane = (tp: 8 tokens, ss: rows interleaved by 4). Same AI as R4 (T=8).
__global__ __launch_bounds__(512, 4) void ff_kernel(
  const float* __restrict__ seq_in, const float* __restrict__ att,
  const float* __restrict__ fcc,
  const float* __restrict__ ow, const float* __restrict__ ob,
  const float* __restrict__ l1w, const float* __restrict__ l1b,
  float* __restrict__ seq_mid, float* __restrict__ ffp, int layer)
{
  __shared__ float wc[512][16];  // 32 KB; aliased as reduce scratch after use
  __shared__ float sM[128][6];
  const int tid   = threadIdx.x;
  const int tile  = blockIdx.x >> 2;
  const int slice = blockIdx.x & 3;
  const int tok0  = tile * 128;

  const float4* FC = (const float4*)(fcc + (size_t)(layer*2048 + slice*512)*16);
  for (int i = tid; i < 2048; i += 512)
    ((float4*)wc)[i] = FC[i];

  if (tid < 128){
    const int token = tok0 + tid;
    const float* a  = att + token*6;
    const float* W  = ow + layer*36;
    float av[6];
    #pragma unroll
    for (int e = 0; e < 6; e++) av[e] = a[e];
    float y[6]; float mu = 0.f;
    #pragma unroll
    for (int e = 0; e < 6; e++){
      float o = ob[layer*6 + e];
      #pragma unroll
      for (int e2 = 0; e2 < 6; e2++) o = fmaf(av[e2], W[e*6 + e2], o);
      y[e] = seq_in[token*6 + e] + o;
      mu += y[e];
    }
    mu *= (1.f/6.f);
    float var = 0.f;
    #pragma unroll
    for (int e = 0; e < 6; e++){ float d = y[e] - mu; var = fmaf(d, d, var); }
    var *= (1.f/6.f);
    float rstd = rsqrtf(var + 1e-5f);
    #pragma unroll
    for (int e = 0; e < 6; e++)
      sM[tid][e] = (y[e] - mu)*rstd*l1w[layer*6 + e] + l1b[layer*6 + e];
  }
  __syncthreads();

  const int w = tid >> 6, lane = tid & 63, tp = lane >> 2, ss = lane & 3;

  float sv[8][6];
  {
    const float* sp = &sM[tp*8][0];
    #pragma unroll
    for (int t = 0; t < 8; t++)
      #pragma unroll
      for (int e = 0; e < 6; e++) sv[t][e] = sp[t*6 + e];
  }
  float acc[8][6];
  #pragma unroll
  for (int t = 0; t < 8; t++)
    #pragma unroll
    for (int e = 0; e < 6; e++) acc[t][e] = 0.f;

  // wave w -> rows [w*64, w*64+64), ss interleaved by 4 (2-way alias = free)
  const int rbase = w*64 + ss;
  #pragma unroll 2
  for (int i = 0; i < 16; i++){
    const float4* wr = (const float4*)&wc[rbase + i*4][0];
    float4 w0 = wr[0], w1 = wr[1], w2 = wr[2], w3 = wr[3];
    #pragma unroll
    for (int t = 0; t < 8; t++){
      float h = w1.z;
      h = fmaf(sv[t][0], w0.x, h); h = fmaf(sv[t][1], w0.y, h);
      h = fmaf(sv[t][2], w0.z, h); h = fmaf(sv[t][3], w0.w, h);
      h = fmaf(sv[t][4], w1.x, h); h = fmaf(sv[t][5], w1.y, h);
      h = relu_(h);
      acc[t][0] = fmaf(h, w2.x, acc[t][0]); acc[t][1] = fmaf(h, w2.y, acc[t][1]);
      acc[t][2] = fmaf(h, w2.z, acc[t][2]); acc[t][3] = fmaf(h, w2.w, acc[t][3]);
      acc[t][4] = fmaf(h, w3.x, acc[t][4]); acc[t][5] = fmaf(h, w3.y, acc[t][5]);
    }
  }

  // reduce across ss on the VALU pipe (DPP)
  #pragma unroll
  for (int t = 0; t < 8; t++)
    #pragma unroll
    for (int e = 0; e < 6; e++){
      acc[t][e] = dpp_xadd1(acc[t][e]);
      acc[t][e] = dpp_xadd2(acc[t][e]);
    }
  __syncthreads();   // all waves done reading wc; reuse as reduce scratch
  float* red = (float*)wc;   // [8 waves][16 tp][48] = 6144 floats <= 8192
  if (ss == 0){
    #pragma unroll
    for (int t = 0; t < 8; t++)
      #pragma unroll
      for (int e = 0; e < 6; e++) red[(w*16 + tp)*48 + t*6 + e] = acc[t][e];
  }
  __syncthreads();
  for (int i = tid; i < 768; i += 512){
    const int tl = i / 6, e = i - tl*6;
    const int rtp = tl >> 3, rt = tl & 7;
    float sum = 0.f;
    #pragma unroll
    for (int wv = 0; wv < 8; wv++)
      sum += red[(wv*16 + rtp)*48 + rt*6 + e];
    ffp[(size_t)(slice*16384 + tok0 + tl)*6 + e] = sum;
  }
  if (slice == 0 && tid < 128){
    #pragma unroll
    for (int e = 0; e < 6; e++) seq_mid[(tok0 + tid)*6 + e] = sM[tid][e];
  }
}

// ------------------- FF-sum + LN2 + next-layer qkv --------------------------
__global__ __launch_bounds__(128) void ffln_kernel(
  const float* __restrict__ seq_mid, const float* __restrict__ ffp,
  const float* __restrict__ f2b, const float* __restrict__ lw,
  const float* __restrict__ lb,
  const float* __restrict__ Wq, const float* __restrict__ Bq,
  float* __restrict__ seq_out, float4* __restrict__ kv4, float2* __restrict__ qq)
{
  const int tok = blockIdx.x*128 + threadIdx.x;
  float y[6]; float mu = 0.f;
  #pragma unroll
  for (int e = 0; e < 6; e++){
    float v = seq_mid[tok*6 + e] + f2b[e];
    v += ffp[(size_t)(0*16384 + tok)*6 + e];
    v += ffp[(size_t)(1*16384 + tok)*6 + e];
    v += ffp[(size_t)(2*16384 + tok)*6 + e];
    v += ffp[(size_t)(3*16384 + tok)*6 + e];
    y[e] = v; mu += v;
  }
  mu *= (1.f/6.f);
  float var = 0.f;
  #pragma unroll
  for (int e = 0; e < 6; e++){ float d = y[e] - mu; var = fmaf(d, d, var); }
  var *= (1.f/6.f);
  float rstd = rsqrtf(var + 1e-5f);
  float sv[6];
  #pragma unroll
  for (int e = 0; e < 6; e++){
    sv[e] = (y[e] - mu)*rstd*lw[e] + lb[e];
    seq_out[tok*6 + e] = sv[e];
  }

  const int n = tok >> 10, t = tok & 1023;
  #pragma unroll
  for (int g = 0; g < 3; g++){
    const int h2 = 2*g;
    float q0 = Bq[h2],   q1 = Bq[h2+1];
    float k0 = Bq[6+h2], k1 = Bq[7+h2];
    float v0 = Bq[12+h2], v1 = Bq[13+h2];
    #pragma unroll
    for (int e = 0; e < 6; e++){
      q0 = fmaf(sv[e], Wq[h2*6 + e],      q0);
      q1 = fmaf(sv[e], Wq[(h2+1)*6 + e],  q1);
      k0 = fmaf(sv[e], Wq[(6+h2)*6 + e],  k0);
      k1 = fmaf(sv[e], Wq[(7+h2)*6 + e],  k1);
      v0 = fmaf(sv[e], Wq[(12+h2)*6 + e], v0);
      v1 = fmaf(sv[e], Wq[(13+h2)*6 + e], v1);
    }
    const int nh = n*3 + g;
    kv4[nh*SL + t] = make_float4(k0*SCQK, k1*SCQK, v0, v1);
    qq [nh*SL + t] = make_float2(q0, q1);
  }
}

// --------------------- head (+ layer-1 FF-sum + LN2) -------------------------
__global__ __launch_bounds__(256) void final_kernel(
  const float* __restrict__ seq_mid, const float* __restrict__ ffp,
  const float* __restrict__ f2b, const float* __restrict__ lw,
  const float* __restrict__ lb,
  const float* __restrict__ o1w, const float* __restrict__ o1b,
  const float* __restrict__ o2w, float* __restrict__ out)
{
  __shared__ float fred[4][6];
  __shared__ float pooled[6];
  const int n = blockIdx.x, tid = threadIdx.x;
  float psum[6] = {0,0,0,0,0,0};

  #pragma unroll
  for (int i = 0; i < 4; i++){
    const int tok = n*SL + tid + i*256;
    float y[6]; float mu = 0.f;
    #pragma unroll
    for (int e = 0; e < 6; e++){
      float v = seq_mid[tok*6 + e] + f2b[e];
      v += ffp[(size_t)(0*16384 + tok)*6 + e];
      v += ffp[(size_t)(1*16384 + tok)*6 + e];
      v += ffp[(size_t)(2*16384 + tok)*6 + e];
      v += ffp[(size_t)(3*16384 + tok)*6 + e];
      y[e] = v; mu += v;
    }
    mu *= (1.f/6.f);
    float var = 0.f;
    #pragma unroll
    for (int e = 0; e < 6; e++){ float d = y[e] - mu; var = fmaf(d, d, var); }
    var *= (1.f/6.f);
    float rstd = rsqrtf(var + 1e-5f);
    #pragma unroll
    for (int e = 0; e < 6; e++)
      psum[e] += (y[e] - mu)*rstd*lw[e] + lb[e];
  }

  #pragma unroll
  for (int e = 0; e < 6; e++){
    psum[e] += __shfl_xor(psum[e], 1);  psum[e] += __shfl_xor(psum[e], 2);
    psum[e] += __shfl_xor(psum[e], 4);  psum[e] += __shfl_xor(psum[e], 8);
    psum[e] += __shfl_xor(psum[e], 16); psum[e] += __shfl_xor(psum[e], 32);
  }
  if ((tid & 63) == 0){
    #pragma unroll
    for (int e = 0; e < 6; e++) fred[tid >> 6][e] = psum[e];
  }
  __syncthreads();
  if (tid < 6){
    float t = fred[0][tid] + fred[1][tid] + fred[2][tid] + fred[3][tid];
    pooled[tid] = fmaxf(t * (1.f/1024.f), 0.f);
  }
  __syncthreads();
  if (tid == 0){
    float o1[7];
    #pragma unroll
    for (int o = 0; o < 7; o++){
      float a = o1b[o];
      #pragma unroll
      for (int e2 = 0; e2 < 6; e2++) a = fmaf(pooled[e2], o1w[o*6 + e2], a);
      o1[o] = relu_(a);
    }
    float lg[4];
    #pragma unroll
    for (int c = 0; c < 4; c++){
      float a = 0.f;
      #pragma unroll
      for (int o = 0; o < 7; o++) a = fmaf(o1[o], o2w[c*7 + o], a);
      lg[c] = a;
    }
    float m = fmaxf(fmaxf(lg[0], lg[1]), fmaxf(lg[2], lg[3]));
    float sum = 0.f;
    #pragma unroll
    for (int c = 0; c < 4; c++) sum += expf(lg[c] - m);
    float lse = m + logf(sum);
    #pragma unroll
    for (int c = 0; c < 4; c++) out[n*4 + c] = lg[c] - lse;
  }
}

// ------------------------------- launch --------------------------------------
extern "C" void kernel_launch(void* const* d_in, const int* in_sizes, int n_in,
                              void* d_out, int out_size, void* d_ws, size_t ws_size,
                              hipStream_t stream)
{
  const float* x    = (const float*)d_in[0];
  const float* k64  = (const float*)d_in[1];
  const float* b64  = (const float*)d_in[2];
  const float* k16  = (const float*)d_in[3];
  const float* b16  = (const float*)d_in[4];
  const float* k8   = (const float*)d_in[5];
  const float* b8   = (const float*)d_in[6];
  const float* kw3  = (const float*)d_in[7];
  const float* bw3  = (const float*)d_in[8];
  const float* km3  = (const float*)d_in[9];
  const float* bm3  = (const float*)d_in[10];
  const float* kn3  = (const float*)d_in[11];
  const float* bn3  = (const float*)d_in[12];
  const float* fc1w = (const float*)d_in[13];
  const float* fc1b = (const float*)d_in[14];
  const float* fc2w = (const float*)d_in[15];
  const float* fc2b = (const float*)d_in[16];
  const float* inw  = (const float*)d_in[17];
  const float* inb  = (const float*)d_in[18];
  const float* ow   = (const float*)d_in[19];
  const float* ob   = (const float*)d_in[20];
  const float* l1w  = (const float*)d_in[21];
  const float* l1b  = (const float*)d_in[22];
  const float* l2w  = (const float*)d_in[23];
  const float* l2b  = (const float*)d_in[24];
  const float* f1w  = (const float*)d_in[25];
  const float* f1b  = (const float*)d_in[26];
  const float* f2w  = (const float*)d_in[27];
  const float* f2b  = (const float*)d_in[28];
  const float* o1w  = (const float*)d_in[29];
  const float* o1b  = (const float*)d_in[30];
  const float* o2w  = (const float*)d_in[31];
  float* out = (float*)d_out;

  float* w = (float*)d_ws;
  float*  seq_a   = w;                       // 98304
  float*  seq_b   = w + 98304;               // 98304
  float*  att     = w + 196608;              // 98304
  float*  seq_mid = w + 294912;              // 98304
  float*  ffp     = w + 393216;              // 393216
  float*  fcc     = w + 786432;              // 65536
  float4* kv4     = (float4*)(w + 851968);   // 196608 floats
  float2* qq      = (float2*)(w + 1048576);  // 98304 floats
  // total 1146880 floats ~= 4.6 MB

  frontend_kernel<<<256, 192, 0, stream>>>(x, k64, b64, k16, b16, k8, b8,
      kw3, bw3, km3, bm3, kn3, bn3, fc1w, fc1b, fc2w, fc2b,
      f1w, f1b, f2w, inw, inb, fcc, seq_a, kv4, qq);

  dim3 agrid(16, 3, 16);
  attn_kernel<<<agrid, 512, 0, stream>>>(kv4, qq, att);
  ff_kernel<<<512, 512, 0, stream>>>(seq_a, att, fcc, ow, ob, l1w, l1b,
      seq_mid, ffp, 0);
  ffln_kernel<<<128, 128, 0, stream>>>(seq_mid, ffp, f2b, l2w, l2b,
      inw + 108, inb + 18, seq_b, kv4, qq);

  attn_kernel<<<agrid, 512, 0, stream>>>(kv4, qq, att);
  ff_kernel<<<512, 512, 0, stream>>>(seq_b, att, fcc, ow, ob, l1w, l1b,
      seq_mid, ffp, 1);
  final_kernel<<<16, 256, 0, stream>>>(seq_mid, ffp, f2b + 6, l2w + 6, l2b + 6,
      o1w, o1b, o2w, out);
}